// Round 3
// baseline (335.673 us; speedup 1.0000x reference)
//
#include <hip/hip_runtime.h>

// WeightedSumSessEmbedding: out[s,:] = sum_{j: row_idx[j]==s} data[j] * emb[col_idx[j],:]
// row_idx sorted. Two kernels:
//   1) build_rowptr: CSR row_ptr[num_sess+1] in d_ws (each entry written
//      exactly once -> deterministic, no init needed).
//   2) wsum: ONE WAVE PER SESSION, lane = embedding dim (64 dims = 64 lanes,
//      4B/lane -> one gather instruction reads exactly one 256B row, fully
//      coalesced). Per 64-nnz batch: one coalesced col/data load, then
//      readlane-broadcast col_k/w_k to SGPRs and issue 32 INDEPENDENT row
//      gathers back-to-back before the FMAs -> ~32 loads in flight per wave
//      (vs ~8 before), address math on the scalar unit.
// No atomics, out written exactly once -> no zero-init of d_out.

__global__ __launch_bounds__(256) void build_rowptr_kernel(
    const int* __restrict__ row_idx,
    int*       __restrict__ row_ptr,   // [num_sess+1]
    int nnz, int num_sess)
{
    int j = blockIdx.x * blockDim.x + threadIdx.x;
    if (j >= nnz) return;
    int r = row_idx[j];
    if (j == 0) {
        for (int s = 0; s <= r; ++s) row_ptr[s] = 0;
    } else {
        int rp = row_idx[j - 1];
        for (int s = rp + 1; s <= r; ++s) row_ptr[s] = j;
    }
    if (j == nnz - 1) {
        for (int s = r + 1; s <= num_sess; ++s) row_ptr[s] = nnz;
    }
}

__global__ __launch_bounds__(256, 8) void wsum_sess_kernel(
    const int*   __restrict__ row_ptr,
    const int*   __restrict__ col_idx,
    const float* __restrict__ data,
    const float* __restrict__ emb,    // [ITEMS_NUM, 64]
    float*       __restrict__ out,    // [num_sess, 64]
    int num_sess)
{
    const int wave = threadIdx.x >> 6;           // 0..3
    const int lane = threadIdx.x & 63;           // = embedding dim
    const int sess = (blockIdx.x << 2) + wave;   // one wave per session
    if (sess >= num_sess) return;                // wave-uniform

    const int start = row_ptr[sess];
    const int end   = row_ptr[sess + 1];

    float acc = 0.0f;

    for (int j0 = start; j0 < end; j0 += 64) {
        const int jl    = j0 + lane;
        const bool valid = (jl < end);
        // one coalesced load each for 64 cols / 64 weights
        int   col = valid ? col_idx[jl] : 0;
        float w   = valid ? data[jl]    : 0.0f;   // invalid lanes contribute 0
        const int rem = end - j0;                 // valid nnz in this batch

        // two chunks of 32 nnz; chunk-level branch is wave-uniform
        #pragma unroll
        for (int kb = 0; kb < 64; kb += 32) {
            if (kb >= rem) break;
            float v[32];
            float wk[32];
            #pragma unroll
            for (int k = 0; k < 32; ++k) {
                // compile-time lane index -> v_readlane to SGPR; address math
                // is scalar, gather base is wave-uniform + lane*4
                int c = __builtin_amdgcn_readlane(col, kb + k);
                wk[k] = __int_as_float(
                            __builtin_amdgcn_readlane(__float_as_int(w), kb + k));
                v[k] = emb[(size_t)c * 64 + lane];
            }
            #pragma unroll
            for (int k = 0; k < 32; ++k)
                acc += wk[k] * v[k];              // SGPR weight operand
        }
    }

    out[(size_t)sess * 64 + lane] = acc;
}

extern "C" void kernel_launch(void* const* d_in, const int* in_sizes, int n_in,
                              void* d_out, int out_size, void* d_ws, size_t ws_size,
                              hipStream_t stream) {
    const int*   row_idx = (const int*)  d_in[0];
    const int*   col_idx = (const int*)  d_in[1];
    const float* data    = (const float*)d_in[2];
    const float* emb     = (const float*)d_in[4];

    const int nnz      = in_sizes[0];
    const int num_sess = out_size / 64;   // EMB_DIM = 64

    int* row_ptr = (int*)d_ws;            // (num_sess+1) ints

    build_rowptr_kernel<<<(nnz + 255) / 256, 256, 0, stream>>>(
        row_idx, row_ptr, nnz, num_sess);

    const int blocks = (num_sess + 3) / 4;   // 4 waves/block, 1 session/wave
    wsum_sess_kernel<<<blocks, 256, 0, stream>>>(
        row_ptr, col_idx, data, emb, (float*)d_out, num_sess);
}